// Round 8
// baseline (199.389 us; speedup 1.0000x reference)
//
#include <hip/hip_runtime.h>

// SAR quantizer: q, Q, Wn outputs.
// L=524288 rows, A=24 ADCs, B=8 bits, M=36 coefficient rows.
// VR = VREF = 1.8 / 2^3 = 0.225, noise scale = 0.01**0.5 = 0.1.
//
// R8 change (arithmetic per element untouched — still bit-exact):
//  - Unroll-2 over the grid-stride: each thread processes elements i and
//    i+T per loop iteration (same ADC column since T%24==0 -> shared c[]).
//    Doubles per-wave in-flight VMEM (2 loads + 6 stores ~ 4.5KB) and
//    gives 2x ILP on the serial SAR chain. Theory: we are memory-request-
//    parallelism-bound (eff BW scaled with waves: 3.6 TB/s @24w -> 5.0
//    @32w; prefetch depth +1 -> small win; compute ~40us << 96us).
//  - Two 2KB LDS stage buffers per wave (A/B within iteration).
//  - __launch_bounds__(384, 8) pins VGPR <= 64 (occupancy cliff at 64).

#define L_TOT   524288
#define A_ADC   24
#define M_ROWS  36
#define B_BITS  8
#define BLK     384
#define NBLK    2048
#define NXCD    8

typedef float f32x4 __attribute__((ext_vector_type(4)));

// XOR bank-quad swizzle (involution, bijective on [0,128)).
__device__ __forceinline__ int swz(int c) { return c ^ ((c >> 3) & 7); }

__global__ __launch_bounds__(BLK, 8) void sar_kernel(
    const float* __restrict__ x,
    const float* __restrict__ W,
    const float* __restrict__ nz,
    float* __restrict__ out_q,
    float* __restrict__ out_Q,
    float* __restrict__ out_Wn,
    long long N)
{
    // Bijective XCD swizzle (NBLK % 8 == 0).
    const int bid = blockIdx.x;
    const int sb  = (bid & (NXCD - 1)) * (NBLK / NXCD) + (bid >> 3);

    const long long gid = (long long)sb * BLK + threadIdx.x;
    const long long T   = (long long)NBLK * BLK;   // 786432 = 24 * 32768
    const int a = threadIdx.x % 24;  // fixed ADC column (BLK % 24 == 0)
    const int w = threadIdx.x >> 6;  // wave id in block (0..5)
    const int l = threadIdx.x & 63;  // lane

    __shared__ f32x4 stage[BLK / 64][2][128]; // 2 x 2KB per wave

    // Per-a coefficients: c[r] = (W[r][a] + noise[r][a]*0.1f) * 0.225f
    float c[M_ROWS];
#pragma unroll
    for (int r = 0; r < M_ROWS; ++r) {
        float wn = W[r * A_ADC + a] + nz[r * A_ADC + a] * 0.1f;
        c[r] = wn * 0.225f;
    }

    // Wn tail output (864 floats), once (gid is a bijection of thread id).
    if (gid < (long long)(M_ROWS * A_ADC)) {
        __builtin_nontemporal_store(W[gid] + nz[gid] * 0.1f, &out_Wn[gid]);
    }

    // Pipeline: xv0 = x[i], xv1 = x[i+T]; prefetch next pair each iter.
    float xv0 = (gid < N)     ? x[gid]     : 0.0f;
    float xv1 = (gid + T < N) ? x[gid + T] : 0.0f;

    // N % (2T) == 0 and every element gid + m*T (m=0..15) is covered:
    // iteration k handles m=2k and m=2k+1. Exactly 8 iterations.
    for (long long i = gid; i < N; i += 2 * T) {
        // Prefetch the next pair FIRST (oldest in VMEM queue).
        const long long ip0 = i + 2 * T, ip1 = i + 3 * T;
        float xn0 = 0.0f, xn1 = 0.0f;
        if (ip0 < N) xn0 = x[ip0];
        if (ip1 < N) xn1 = x[ip1];

        // Two independent SAR chains, interleaved for ILP.
        float t0[B_BITS], t1[B_BITS];   // t = (q+1)/2 in {0, 0.5, 1}
        int m = M_ROWS - 1;
#pragma unroll
        for (int jj = 0; jj < B_BITS; ++jj) {
            const int j = B_BITS - 1 - jj;
            float bs0 = c[m], bs1 = c[m]; --m;      // Wn[m]*VREF
#pragma unroll
            for (int k = j + 1; k < B_BITS; ++k) {
                // t_k * c[m]: exact (t is a pow2 scale), k-ascending order
                // identical to reference accumulation.
                bs0 += t0[k] * c[m];
                bs1 += t1[k] * c[m];
                --m;
            }
            float s0 = (xv0 - bs0) + 1e-30f;
            float s1 = (xv1 - bs1) + 1e-30f;
            float q0 = (s0 > 0.0f) ? 1.0f : ((s0 < 0.0f) ? -1.0f : 0.0f);
            float q1 = (s1 > 0.0f) ? 1.0f : ((s1 < 0.0f) ? -1.0f : 0.0f);
            t0[j] = (q0 + 1.0f) * 0.5f;
            t1[j] = (q1 + 1.0f) * 0.5f;
        }

        // q = sum_j t_j * (0.225 * 2^j), ascending j (same fp order as ref).
        float acc0 = 0.0f, acc1 = 0.0f;
#pragma unroll
        for (int j = 0; j < B_BITS; ++j) {
            float bwj = 0.225f * (float)(1 << j);  // exact pow2 scaling
            acc0 += t0[j] * bwj;
            acc1 += t1[j] * bwj;
        }
        __builtin_nontemporal_store(acc0, &out_q[i]);
        __builtin_nontemporal_store(acc1, &out_q[i + T]);

        // --- Q output via LDS staging (q_j = 2*t_j - 1, exact) ---
        f32x4 a0, a1, b0, b1;
        a0.x = 2.0f*t0[0]-1.0f; a0.y = 2.0f*t0[1]-1.0f; a0.z = 2.0f*t0[2]-1.0f; a0.w = 2.0f*t0[3]-1.0f;
        a1.x = 2.0f*t0[4]-1.0f; a1.y = 2.0f*t0[5]-1.0f; a1.z = 2.0f*t0[6]-1.0f; a1.w = 2.0f*t0[7]-1.0f;
        b0.x = 2.0f*t1[0]-1.0f; b0.y = 2.0f*t1[1]-1.0f; b0.z = 2.0f*t1[2]-1.0f; b0.w = 2.0f*t1[3]-1.0f;
        b1.x = 2.0f*t1[4]-1.0f; b1.y = 2.0f*t1[5]-1.0f; b1.z = 2.0f*t1[6]-1.0f; b1.w = 2.0f*t1[7]-1.0f;
        const int c0 = 2 * l, c1 = 2 * l + 1;
        stage[w][0][swz(c0)] = a0;
        stage[w][0][swz(c1)] = a1;
        stage[w][1][swz(c0)] = b0;
        stage[w][1][swz(c1)] = b1;
        // wave-private; DS pipe is in-order within a wave.
        const long long baseA = i - l;          // wave's first element, elem A
        const long long baseB = i + T - l;      // elem B
        f32x4* QA = (f32x4*)(out_Q + baseA * 8);
        f32x4* QB = (f32x4*)(out_Q + baseB * 8);
        const int r0 = l, r1 = 64 + l;
        __builtin_nontemporal_store(stage[w][0][swz(r0)], &QA[r0]);
        __builtin_nontemporal_store(stage[w][0][swz(r1)], &QA[r1]);
        __builtin_nontemporal_store(stage[w][1][swz(r0)], &QB[r0]);
        __builtin_nontemporal_store(stage[w][1][swz(r1)], &QB[r1]);

        xv0 = xn0;
        xv1 = xn1;
    }
}

extern "C" void kernel_launch(void* const* d_in, const int* in_sizes, int n_in,
                              void* d_out, int out_size, void* d_ws, size_t ws_size,
                              hipStream_t stream) {
    const float* x  = (const float*)d_in[0];
    const float* W  = (const float*)d_in[1];
    const float* nz = (const float*)d_in[2];
    float* out = (float*)d_out;

    const long long N = (long long)L_TOT * A_ADC;   // 12,582,912
    float* out_q  = out;
    float* out_Q  = out + N;
    float* out_Wn = out + N + N * (long long)B_BITS;

    // 2048 blocks x 384 threads; stride T = 786432 (multiple of 24);
    // 8 unroll-2 iterations per thread.
    sar_kernel<<<NBLK, BLK, 0, stream>>>(x, W, nz, out_q, out_Q, out_Wn, N);
}

// Round 9
// 95.612 us; speedup vs baseline: 2.0854x; 2.0854x over previous
//
#include <hip/hip_runtime.h>

// SAR quantizer: q, Q, Wn outputs.
// L=524288 rows, A=24 ADCs, B=8 bits, M=36 coefficient rows.
// VR = VREF = 1.8 / 2^3 = 0.225, noise scale = 0.01**0.5 = 0.1.
//
// R9: unroll-2 retried WITHOUT the R8 occupancy clamp (which forced VGPR=32
// and spilled: FETCH 25->293MB). Register pressure cut via bitmask SAR state:
//   sign(x - bs + 1e-30) == (x >= bs ? +1 : -1) EXACTLY for these inputs
//   (f32 diffs of normal-range values are 0 or >=~1e-9; +1e-30 only decides
//   the ==0 case). t=(q+1)/2 is then {0,1}: bs += bit?c[m]:0.0f and
//   acc += bit?bw[j]:0.0f are bit-exact vs the reference's t*c / t*bw
//   (adding +-0.0 never changes a value observably).
// Each element's state = 1 bitmask reg (was 8 float regs) -> unroll-2 fits
// ~50 VGPRs, keeping 32 waves/CU. 2 loads + 6 stores (~4.6KB) in flight
// per wave-iter, 8 iters/thread.

#define L_TOT   524288
#define A_ADC   24
#define M_ROWS  36
#define B_BITS  8
#define BLK     384
#define NBLK    2048
#define NXCD    8
#define N_TOT   (L_TOT * A_ADC)          // 12,582,912
#define T_STR   (NBLK * BLK)             // 786,432 (multiple of 24); N = 16*T

typedef float f32x4 __attribute__((ext_vector_type(4)));

// XOR bank-quad swizzle (involution, bijective on [0,128)).
__device__ __forceinline__ int swz(int c) { return c ^ ((c >> 3) & 7); }

__global__ __launch_bounds__(BLK) void sar_kernel(
    const float* __restrict__ x,
    const float* __restrict__ W,
    const float* __restrict__ nz,
    float* __restrict__ out_q,
    float* __restrict__ out_Q,
    float* __restrict__ out_Wn)
{
    // Bijective XCD swizzle (NBLK % 8 == 0).
    const int bid = blockIdx.x;
    const int sb  = (bid & (NXCD - 1)) * (NBLK / NXCD) + (bid >> 3);

    const int gid = sb * BLK + threadIdx.x;   // < T_STR < N_TOT; 32-bit safe
    const int a = threadIdx.x % 24;  // fixed ADC column (BLK % 24 == 0)
    const int w = threadIdx.x >> 6;  // wave id in block (0..5)
    const int l = threadIdx.x & 63;  // lane

    __shared__ f32x4 stage[BLK / 64][2][128]; // 2 x 2KB per wave

    // Per-a coefficients: c[r] = (W[r][a] + noise[r][a]*0.1f) * 0.225f
    float c[M_ROWS];
#pragma unroll
    for (int r = 0; r < M_ROWS; ++r) {
        float wn = W[r * A_ADC + a] + nz[r * A_ADC + a] * 0.1f;
        c[r] = wn * 0.225f;
    }

    // Wn tail output (864 floats), once (gid is a bijection of thread id).
    if (gid < M_ROWS * A_ADC) {
        __builtin_nontemporal_store(W[gid] + nz[gid] * 0.1f, &out_Wn[gid]);
    }

    // Pipeline: xv0 = x[i], xv1 = x[i+T]; prefetch next pair each iter.
    float xv0 = x[gid];
    float xv1 = x[gid + T_STR];

    // Exactly 8 iterations; element m*T+gid covered with m=2k (A) and 2k+1 (B).
#pragma unroll 1
    for (int k = 0; k < 8; ++k) {
        const int i = gid + k * 2 * T_STR;

        // Prefetch the next pair FIRST (oldest position in VMEM queue).
        float xn0 = 0.0f, xn1 = 0.0f;
        if (k < 7) {                  // uniform branch
            xn0 = x[i + 2 * T_STR];
            xn1 = x[i + 3 * T_STR];
        }

        // Two independent SAR chains (bitmask state), interleaved for ILP.
        unsigned m0 = 0u, m1 = 0u;    // bit j set => q_j = +1
        int m = M_ROWS - 1;
#pragma unroll
        for (int jj = 0; jj < B_BITS; ++jj) {
            const int j = B_BITS - 1 - jj;
            float bs0 = c[m], bs1 = c[m]; --m;   // Wn[m]*VREF
#pragma unroll
            for (int kk = j + 1; kk < B_BITS; ++kk) {
                bs0 += ((m0 >> kk) & 1u) ? c[m] : 0.0f;
                bs1 += ((m1 >> kk) & 1u) ? c[m] : 0.0f;
                --m;
            }
            if (xv0 >= bs0) m0 |= (1u << j);
            if (xv1 >= bs1) m1 |= (1u << j);
        }

        // q = sum_j bit_j * (0.225 * 2^j), ascending j (bit-exact vs ref).
        float acc0 = 0.0f, acc1 = 0.0f;
#pragma unroll
        for (int j = 0; j < B_BITS; ++j) {
            const float bwj = 0.225f * (float)(1 << j);
            acc0 += ((m0 >> j) & 1u) ? bwj : 0.0f;
            acc1 += ((m1 >> j) & 1u) ? bwj : 0.0f;
        }
        __builtin_nontemporal_store(acc0, &out_q[i]);
        __builtin_nontemporal_store(acc1, &out_q[i + T_STR]);

        // --- Q output via LDS staging (q_j = bit ? +1 : -1) ---
        f32x4 a0, a1, b0, b1;
#pragma unroll
        for (int j = 0; j < 4; ++j) {
            a0[j] = ((m0 >> j) & 1u)       ? 1.0f : -1.0f;
            a1[j] = ((m0 >> (j + 4)) & 1u) ? 1.0f : -1.0f;
            b0[j] = ((m1 >> j) & 1u)       ? 1.0f : -1.0f;
            b1[j] = ((m1 >> (j + 4)) & 1u) ? 1.0f : -1.0f;
        }
        const int c0 = 2 * l, c1 = 2 * l + 1;
        stage[w][0][swz(c0)] = a0;
        stage[w][0][swz(c1)] = a1;
        stage[w][1][swz(c0)] = b0;
        stage[w][1][swz(c1)] = b1;
        // wave-private; compiler inserts lgkmcnt before the readback.
        const int baseA = i - l;              // wave's first element (A)
        const int baseB = i + T_STR - l;      // (B)
        f32x4* QA = (f32x4*)out_Q + baseA * 2;   // f32x4 index space (x2/elem)
        f32x4* QB = (f32x4*)out_Q + baseB * 2;
        const int r0 = l, r1 = 64 + l;
        __builtin_nontemporal_store(stage[w][0][swz(r0)], &QA[r0]);
        __builtin_nontemporal_store(stage[w][0][swz(r1)], &QA[r1]);
        __builtin_nontemporal_store(stage[w][1][swz(r0)], &QB[r0]);
        __builtin_nontemporal_store(stage[w][1][swz(r1)], &QB[r1]);

        xv0 = xn0;
        xv1 = xn1;
    }
}

extern "C" void kernel_launch(void* const* d_in, const int* in_sizes, int n_in,
                              void* d_out, int out_size, void* d_ws, size_t ws_size,
                              hipStream_t stream) {
    const float* x  = (const float*)d_in[0];
    const float* W  = (const float*)d_in[1];
    const float* nz = (const float*)d_in[2];
    float* out = (float*)d_out;

    float* out_q  = out;
    float* out_Q  = out + (long long)N_TOT;
    float* out_Wn = out + (long long)N_TOT * 9;

    // 2048 blocks x 384 threads; 8 unroll-2 iterations per thread.
    sar_kernel<<<NBLK, BLK, 0, stream>>>(x, W, nz, out_q, out_Q, out_Wn);
}